// Round 8
// baseline (320.954 us; speedup 1.0000x reference)
//
#include <hip/hip_runtime.h>

typedef float  f32x4  __attribute__((ext_vector_type(4)));
typedef __bf16 bf16x8 __attribute__((ext_vector_type(8)));
typedef short  s16x4  __attribute__((ext_vector_type(4)));
typedef short  s16x8  __attribute__((ext_vector_type(8)));

static constexpr int B_ = 2, S_ = 2048, E_ = 768, H_ = 12, D_ = 64;
static constexpr int ROWS = B_ * S_;   // 4096
static constexpr int QKVN = 3 * E_;    // 2304
static constexpr int F_   = 4 * E_;    // 3072
static constexpr int BH_  = B_ * H_;   // 24

__device__ __forceinline__ unsigned short f2bf(float f) {
  union { float f; unsigned u; } v; v.f = f;
  unsigned r = v.u + 0x7FFFu + ((v.u >> 16) & 1u);
  return (unsigned short)(r >> 16);
}
__device__ __forceinline__ unsigned pk2(float a, float b) {
  return (unsigned)f2bf(a) | ((unsigned)f2bf(b) << 16);
}
// truncating bf16 pack (cheap; used only for P in softmax)
__device__ __forceinline__ unsigned pk2t(float a, float b) {
  union { float f; unsigned u; } x, y; x.f = a; y.f = b;
  return (x.u >> 16) | (y.u & 0xFFFF0000u);
}
__device__ __forceinline__ f32x4 mfma16(bf16x8 a, bf16x8 b, f32x4 c) {
  return __builtin_amdgcn_mfma_f32_16x16x32_bf16(a, b, c, 0, 0, 0);
}
__device__ __forceinline__ f32x4 mfma16k16(s16x4 a, s16x4 b, f32x4 c) {
  return __builtin_amdgcn_mfma_f32_16x16x16bf16_1k(a, b, c, 0, 0, 0);
}
typedef __attribute__((address_space(3))) unsigned int lds_u32;
typedef const __attribute__((address_space(1))) unsigned int glob_u32;
__device__ __forceinline__ void async_cp16(const unsigned short* g, unsigned short* l) {
  __builtin_amdgcn_global_load_lds((glob_u32*)g, (lds_u32*)l, 16, 0, 0);
}

// ---- fused: all 6 weight transposes (fp32->bf16, W(KxN)->Wt(NxK)) + bias pack ----
struct TD { const float* src; unsigned short* dst; int K; int N; int start; };
__global__ void k_tall(TD d0, TD d1, TD d2, TD d3, TD d4, TD d5,
                       const float* __restrict__ bq, const float* __restrict__ bk,
                       const float* __restrict__ bv, float* __restrict__ bqkv,
                       int nTot) {
  int bid = blockIdx.x;
  if (bid >= nTot) {  // tail block: pack QKV bias
    int t = threadIdx.y * 32 + threadIdx.x;
    for (int i = t; i < E_; i += 256) {
      bqkv[i] = bq[i]; bqkv[E_ + i] = bk[i]; bqkv[2 * E_ + i] = bv[i];
    }
    return;
  }
  TD d = d0;
  if (bid >= d1.start) d = d1;
  if (bid >= d2.start) d = d2;
  if (bid >= d3.start) d = d3;
  if (bid >= d4.start) d = d4;
  if (bid >= d5.start) d = d5;
  int local = bid - d.start;
  int tpr = d.N / 32;
  int nb = (local % tpr) * 32, kb = (local / tpr) * 32;
  __shared__ float tile[32][33];
  int tx = threadIdx.x, ty = threadIdx.y;
#pragma unroll
  for (int i = 0; i < 4; i++)
    tile[ty + 8 * i][tx] = d.src[(size_t)(kb + ty + 8 * i) * d.N + nb + tx];
  __syncthreads();
#pragma unroll
  for (int i = 0; i < 4; i++)
    d.dst[(size_t)(nb + ty + 8 * i) * d.K + kb + tx] = f2bf(tile[tx][ty + 8 * i]);
}

// ---- rearrange K and V into MFMA-fragment-ordered global buffers ----
__global__ __launch_bounds__(256) void k_prep(const unsigned short* __restrict__ qkv,
                                              unsigned short* __restrict__ KF,
                                              unsigned short* __restrict__ VF) {
  int t = blockIdx.x, bh = blockIdx.y, b = bh / H_, h = bh % H_;
  int tid = threadIdx.x;
  size_t tileBase = ((size_t)bh * 32 + t) * 4096;
  for (int it = tid; it < 512; it += 256) {
    int c = it >> 6, lane = it & 63, l15 = lane & 15, quad = lane >> 4;
    int i = c >> 1, half = c & 1;
    const unsigned short* src = qkv + (size_t)(b * S_ + t * 64 + i * 16 + l15) * QKVN
                                + E_ + h * D_ + half * 32 + quad * 8;
    *(uint4*)(KF + tileBase + (size_t)it * 8) = *(const uint4*)src;
  }
  __shared__ __align__(16) unsigned short Vt[64][72];
  for (int it = tid; it < 512; it += 256) {
    int r = it >> 3, seg = it & 7;
    const unsigned short* src = qkv + (size_t)(b * S_ + t * 64 + r) * QKVN
                                + 2 * E_ + h * D_ + seg * 8;
    *(uint4*)&Vt[r][seg * 8] = *(const uint4*)src;
  }
  __syncthreads();
  for (int it = tid; it < 512; it += 256) {
    int c = it >> 6, lane = it & 63, l15 = lane & 15, quad = lane >> 4;
    int ipair = c >> 2, ds = c & 3;
    int d = ds * 16 + l15;
    unsigned short v[8];
#pragma unroll
    for (int j = 0; j < 4; j++) {
      v[j]     = Vt[ipair * 32 + quad * 4 + j][d];
      v[4 + j] = Vt[ipair * 32 + 16 + quad * 4 + j][d];
    }
    uint4 w;
    w.x = v[0] | ((unsigned)v[1] << 16);
    w.y = v[2] | ((unsigned)v[3] << 16);
    w.z = v[4] | ((unsigned)v[5] << 16);
    w.w = v[6] | ((unsigned)v[7] << 16);
    *(uint4*)(VF + tileBase + (size_t)it * 8) = w;
  }
}

// ---- LayerNorm over E=768, one block per row, bf16 out ----
__global__ __launch_bounds__(256) void k_ln(const float* __restrict__ x,
                                            const float* __restrict__ g,
                                            const float* __restrict__ bta,
                                            unsigned short* __restrict__ y) {
  int row = blockIdx.x;
  const float* xr = x + (size_t)row * E_;
  int t = threadIdx.x;
  float v0 = xr[t], v1 = xr[t + 256], v2 = xr[t + 512];
  float s = v0 + v1 + v2, q = v0 * v0 + v1 * v1 + v2 * v2;
#pragma unroll
  for (int off = 1; off < 64; off <<= 1) {
    s += __shfl_xor(s, off);
    q += __shfl_xor(q, off);
  }
  __shared__ float ss[4], qq[4];
  int wave = t >> 6;
  if ((t & 63) == 0) { ss[wave] = s; qq[wave] = q; }
  __syncthreads();
  s = ss[0] + ss[1] + ss[2] + ss[3];
  q = qq[0] + qq[1] + qq[2] + qq[3];
  float mean = s * (1.0f / E_);
  float var  = q * (1.0f / E_) - mean * mean;
  float inv  = rsqrtf(var + 1e-5f);
  unsigned short* yr = y + (size_t)row * E_;
  yr[t]       = f2bf((v0 - mean) * inv * g[t]       + bta[t]);
  yr[t + 256] = f2bf((v1 - mean) * inv * g[t + 256] + bta[t + 256]);
  yr[t + 512] = f2bf((v2 - mean) * inv * g[t + 512] + bta[t + 512]);
}

// ---- fused split-K reduce + residual + LayerNorm ----
__global__ __launch_bounds__(256) void k_redln(const float* __restrict__ pA,
                                               const float* __restrict__ pB,
                                               const float* __restrict__ bias,
                                               const float* __restrict__ resid,
                                               const float* __restrict__ g,
                                               const float* __restrict__ bta,
                                               float* __restrict__ y,
                                               unsigned short* __restrict__ z) {
  int row = blockIdx.x;
  size_t base = (size_t)row * E_;
  int t = threadIdx.x;
  float v0 = pA[base + t]       + pB[base + t]       + bias[t]       + resid[base + t];
  float v1 = pA[base + t + 256] + pB[base + t + 256] + bias[t + 256] + resid[base + t + 256];
  float v2 = pA[base + t + 512] + pB[base + t + 512] + bias[t + 512] + resid[base + t + 512];
  y[base + t] = v0; y[base + t + 256] = v1; y[base + t + 512] = v2;
  float s = v0 + v1 + v2, q = v0 * v0 + v1 * v1 + v2 * v2;
#pragma unroll
  for (int off = 1; off < 64; off <<= 1) {
    s += __shfl_xor(s, off);
    q += __shfl_xor(q, off);
  }
  __shared__ float ss[4], qq[4];
  int wave = t >> 6;
  if ((t & 63) == 0) { ss[wave] = s; qq[wave] = q; }
  __syncthreads();
  s = ss[0] + ss[1] + ss[2] + ss[3];
  q = qq[0] + qq[1] + qq[2] + qq[3];
  float mean = s * (1.0f / E_);
  float var  = q * (1.0f / E_) - mean * mean;
  float inv  = rsqrtf(var + 1e-5f);
  unsigned short* zr = z + base;
  zr[t]       = f2bf((v0 - mean) * inv * g[t]       + bta[t]);
  zr[t + 256] = f2bf((v1 - mean) * inv * g[t + 256] + bta[t + 256]);
  zr[t + 512] = f2bf((v2 - mean) * inv * g[t + 512] + bta[t + 512]);
}

// ---- bf16 MFMA GEMM: single-barrier double-buffered pipeline ----
// flags: 1=gelu, 2=+resid, 4=bf16 out, 8=raw fp32 partial (split-K, no bias)
template <int WN>
__global__ __launch_bounds__(WN * 128) void k_gemm2(
    const unsigned short* __restrict__ A, const unsigned short* __restrict__ Bt,
    const float* __restrict__ bias, const float* __restrict__ resid,
    float* __restrict__ outF, unsigned short* __restrict__ outB,
    int M, int N, int K, int kLen, int flags) {
  constexpr int NW = 2 * WN;
  __shared__ __align__(16) unsigned short Alds[2][128 * 32];
  __shared__ __align__(16) unsigned short Blds[2][WN * 64 * 32];
  int tid = threadIdx.x, lane = tid & 63, wave = tid >> 6;
  int l15 = lane & 15, quad = lane >> 4;
  int wm = (WN == 2) ? (wave >> 1) : wave;
  int wn = (WN == 2) ? (wave & 1) : 0;
  int mblk = blockIdx.y * 128;
  int nblk = blockIdx.x * (WN * 64);
  int kOff = blockIdx.z * kLen;
  if (flags & 8) outF += (size_t)blockIdx.z * M * N;

  f32x4 acc[4][4];
#pragma unroll
  for (int i = 0; i < 4; i++)
#pragma unroll
    for (int j = 0; j < 4; j++)
#pragma unroll
      for (int r = 0; r < 4; r++) acc[i][j][r] = 0.0f;

  int lrow = lane >> 2, lcol = (lane & 3) * 8;
  auto stage = [&](int k0, int bufi) {
#pragma unroll
    for (int c = 0; c < 8 / NW; c++) {
      int ch = wave + c * NW;
      async_cp16(A + (size_t)(mblk + ch * 16 + lrow) * K + k0 + lcol,
                 Alds[bufi] + ch * 512);
    }
#pragma unroll
    for (int c = 0; c < 4 * WN / NW; c++) {
      int ch = wave + c * NW;
      async_cp16(Bt + (size_t)(nblk + ch * 16 + lrow) * K + k0 + lcol,
                 Blds[bufi] + ch * 512);
    }
  };

  int nT = kLen / 32;
  stage(kOff, 0);
  for (int t = 0; t < nT; t++) {
    __syncthreads();  // drains own async stage; all staging complete
    int bufi = t & 1;
    bf16x8 af[4], bfj[4];
#pragma unroll
    for (int i = 0; i < 4; i++)
      af[i] = *(const bf16x8*)&Alds[bufi][(wm * 64 + i * 16 + l15) * 32 + quad * 8];
#pragma unroll
    for (int j = 0; j < 4; j++)
      bfj[j] = *(const bf16x8*)&Blds[bufi][(wn * 64 + j * 16 + l15) * 32 + quad * 8];
    if (t + 1 < nT) stage(kOff + (t + 1) * 32, bufi ^ 1);  // overlap with MFMA
#pragma unroll
    for (int i = 0; i < 4; i++)
#pragma unroll
      for (int j = 0; j < 4; j++)
        acc[i][j] = mfma16(af[i], bfj[j], acc[i][j]);
  }

  int m0 = mblk + wm * 64, n0 = nblk + wn * 64;
#pragma unroll
  for (int i = 0; i < 4; i++) {
#pragma unroll
    for (int j = 0; j < 4; j++) {
      int col = n0 + 16 * j + l15;
      float bcol = (flags & 8) ? 0.0f : bias[col];
#pragma unroll
      for (int r = 0; r < 4; r++) {
        int row = m0 + 16 * i + quad * 4 + r;
        float v = acc[i][j][r] + bcol;
        if (flags & 1) v = 0.5f * v * (1.0f + erff(v * 0.70710678118654752f));
        if (flags & 2) v += resid[(size_t)row * N + col];
        if (flags & 4) outB[(size_t)row * N + col] = f2bf(v);
        else           outF[(size_t)row * N + col] = v;
      }
    }
  }
}

// ---- split-K reduce: out = pA + pB + bias + resid ----
__global__ __launch_bounds__(256) void k_red(const float* __restrict__ pA,
                                             const float* __restrict__ pB,
                                             const float* __restrict__ bias,
                                             const float* __restrict__ resid,
                                             float* __restrict__ out, int N) {
  size_t i = ((size_t)blockIdx.x * 256 + threadIdx.x) * 4;
  int col = (int)(i % N);
  f32x4 a = *(const f32x4*)(pA + i);
  f32x4 b = *(const f32x4*)(pB + i);
  f32x4 c = *(const f32x4*)(bias + col);
  f32x4 r = *(const f32x4*)(resid + i);
  *(f32x4*)(out + i) = a + b + c + r;
}

// ---- flash attention: LDS-staged fragment-ordered K/V, single-barrier dbuf ----
__global__ __launch_bounds__(256, 3) void k_attn(const unsigned short* __restrict__ qkv,
                                                 const unsigned short* __restrict__ KF,
                                                 const unsigned short* __restrict__ VF,
                                                 float* __restrict__ Opart,
                                                 float* __restrict__ Lpart) {
  int bh = blockIdx.y, b = bh / H_, h = bh % H_;
  int ks = blockIdx.z;
  int tid = threadIdx.x, wave = tid >> 6, lane = tid & 63;
  int l15 = lane & 15, quad = lane >> 4;
  int q0 = blockIdx.x * 128 + wave * 32;

  __shared__ __align__(16) unsigned short Kl[2][4096];
  __shared__ __align__(16) unsigned short Vl[2][4096];

  const unsigned short* Qp = qkv + (size_t)b * S_ * QKVN + h * D_;
  bf16x8 qf[2][2];
#pragma unroll
  for (int qs = 0; qs < 2; qs++) {
    const unsigned short* qrow = Qp + (size_t)(q0 + qs * 16 + l15) * QKVN;
    qf[qs][0] = *(const bf16x8*)(qrow + quad * 8);
    qf[qs][1] = *(const bf16x8*)(qrow + 32 + quad * 8);
  }
  f32x4 o[4][2];
  float lsum[2] = {0.0f, 0.0f};
#pragma unroll
  for (int ds = 0; ds < 4; ds++)
#pragma unroll
    for (int qs = 0; qs < 2; qs++)
#pragma unroll
      for (int r = 0; r < 4; r++) o[ds][qs][r] = 0.0f;

  const float C2 = 0.03608439182435161f * 1.44269504088896341f;  // (1/sqrt(E))*log2e
  const unsigned short* KFb = KF + (size_t)bh * 32 * 4096;
  const unsigned short* VFb = VF + (size_t)bh * 32 * 4096;
  int t0 = ks * 16;

  auto stage = [&](int tt, int bufi) {
    const unsigned short* ksrc = KFb + (size_t)tt * 4096;
    const unsigned short* vsrc = VFb + (size_t)tt * 4096;
#pragma unroll
    for (int c = 0; c < 2; c++) {
      int ch = wave * 2 + c;
      async_cp16(ksrc + ch * 512 + lane * 8, Kl[bufi] + ch * 512 + lane * 8);
      async_cp16(vsrc + ch * 512 + lane * 8, Vl[bufi] + ch * 512 + lane * 8);
    }
  };

  stage(t0, 0);
  for (int tt = 0; tt < 16; tt++) {
    __syncthreads();  // staging of tile tt complete; prior reads done
    int bufi = tt & 1;
    bf16x8 kf[8];
    s16x8  vv[8];
#pragma unroll
    for (int c = 0; c < 8; c++)
      kf[c] = *(const bf16x8*)&Kl[bufi][c * 512 + lane * 8];
#pragma unroll
    for (int c = 0; c < 8; c++)
      vv[c] = *(const s16x8*)&Vl[bufi][c * 512 + lane * 8];
    if (tt + 1 < 16) stage(t0 + tt + 1, bufi ^ 1);  // overlap with compute

#pragma unroll
    for (int i = 0; i < 4; i++) {
      f32x4 s0, s1;
#pragma unroll
      for (int r = 0; r < 4; r++) { s0[r] = 0.0f; s1[r] = 0.0f; }
      s0 = mfma16(kf[i * 2], qf[0][0], s0);
      s0 = mfma16(kf[i * 2 + 1], qf[0][1], s0);
      s1 = mfma16(kf[i * 2], qf[1][0], s1);
      s1 = mfma16(kf[i * 2 + 1], qf[1][1], s1);
      float a0 = __builtin_amdgcn_exp2f(s0[0] * C2);
      float a1 = __builtin_amdgcn_exp2f(s0[1] * C2);
      float a2 = __builtin_amdgcn_exp2f(s0[2] * C2);
      float a3 = __builtin_amdgcn_exp2f(s0[3] * C2);
      float b0 = __builtin_amdgcn_exp2f(s1[0] * C2);
      float b1 = __builtin_amdgcn_exp2f(s1[1] * C2);
      float b2 = __builtin_amdgcn_exp2f(s1[2] * C2);
      float b3 = __builtin_amdgcn_exp2f(s1[3] * C2);
      lsum[0] += (a0 + a1) + (a2 + a3);
      lsum[1] += (b0 + b1) + (b2 + b3);
      union { unsigned u[2]; s16x4 s4; } pw0, pw1;
      pw0.u[0] = pk2t(a0, a1); pw0.u[1] = pk2t(a2, a3);
      pw1.u[0] = pk2t(b0, b1); pw1.u[1] = pk2t(b2, b3);
      int cb = (i >> 1) * 4;
#pragma unroll
      for (int ds = 0; ds < 4; ds++) {
        s16x4 vsel = (i & 1)
            ? __builtin_shufflevector(vv[cb + ds], vv[cb + ds], 4, 5, 6, 7)
            : __builtin_shufflevector(vv[cb + ds], vv[cb + ds], 0, 1, 2, 3);
        o[ds][0] = mfma16k16(vsel, pw0.s4, o[ds][0]);
        o[ds][1] = mfma16k16(vsel, pw1.s4, o[ds][1]);
      }
    }
  }

#pragma unroll
  for (int qs = 0; qs < 2; qs++) {
    size_t rb = (((size_t)ks * BH_ + bh) * S_ + q0 + qs * 16 + l15) * (size_t)D_;
#pragma unroll
    for (int ds = 0; ds < 4; ds++)
      *(f32x4*)(Opart + rb + ds * 16 + quad * 4) = o[ds][qs];
  }
  float l0 = lsum[0]; l0 += __shfl_xor(l0, 16); l0 += __shfl_xor(l0, 32);
  float l1 = lsum[1]; l1 += __shfl_xor(l1, 16); l1 += __shfl_xor(l1, 32);
  if (lane < 16) {
    size_t lb = ((size_t)ks * BH_ + bh) * S_ + q0;
    Lpart[lb + l15]      = l0;
    Lpart[lb + 16 + l15] = l1;
  }
}

// ---- attention split-K reduce: ctx = (O0+O1)/(l0+l1), bf16 ----
__global__ __launch_bounds__(256) void k_ared(const float* __restrict__ Op,
                                              const float* __restrict__ Lp,
                                              unsigned short* __restrict__ ctx) {
  const size_t SL = (size_t)BH_ * S_ * D_;
  const size_t LL = (size_t)BH_ * S_;
  size_t i = (size_t)blockIdx.x * 256 + threadIdx.x;
  size_t row = i >> 4;
  int d4 = (int)(i & 15);
  f32x4 a = *(const f32x4*)(Op + row * D_ + d4 * 4);
  f32x4 b = *(const f32x4*)(Op + SL + row * D_ + d4 * 4);
  float inv = 1.0f / (Lp[row] + Lp[LL + row]);
  f32x4 v = (a + b) * inv;
  int bh = (int)(row >> 11), s = (int)(row & (S_ - 1));
  int bb = bh / H_, h = bh % H_;
  uint2 w; w.x = pk2(v[0], v[1]); w.y = pk2(v[2], v[3]);
  *(uint2*)(ctx + ((size_t)bb * S_ + s) * E_ + h * D_ + d4 * 4) = w;
}

extern "C" void kernel_launch(void* const* d_in, const int* in_sizes, int n_in,
                              void* d_out, int out_size, void* d_ws, size_t ws_size,
                              hipStream_t stream) {
  const float* x    = (const float*)d_in[0];
  const float* ln1g = (const float*)d_in[1];
  const float* ln1b = (const float*)d_in[2];
  const float* wq   = (const float*)d_in[3];
  const float* bq   = (const float*)d_in[4];
  const float* wk   = (const float*)d_in[5];
  const float* bk   = (const float*)d_in[6];
  const float* wv   = (const float*)d_in[7];
  const float* bv   = (const float*)d_in[8];
  const float* wo   = (const float*)d_in[9];
  const float* bo   = (const float*)d_in[10];
  const float* w1   = (const float*)d_in[11];
  const float* b1   = (const float*)d_in[12];
  const float* w2   = (const float*)d_in[13];
  const float* b2   = (const float*)d_in[14];
  const float* ln2g = (const float*)d_in[15];
  const float* ln2b = (const float*)d_in[16];
  float* out = (float*)d_out;

  char* ws = (char*)d_ws;
  size_t off = 0;
  auto alloc = [&](size_t bytes) -> char* {
    char* p = ws + off;
    off = (off + bytes + 255) & ~(size_t)255;
    return p;
  };
  unsigned short* y1    = (unsigned short*)alloc((size_t)ROWS * E_ * 2);
  unsigned short* wtqkv = (unsigned short*)alloc((size_t)QKVN * E_ * 2);
  float*          bqkv  = (float*)alloc((size_t)QKVN * 4);
  unsigned short* qkv   = (unsigned short*)alloc((size_t)ROWS * QKVN * 2);
  unsigned short* wto   = (unsigned short*)alloc((size_t)E_ * E_ * 2);
  unsigned short* ctx   = (unsigned short*)alloc((size_t)ROWS * E_ * 2);
  float*          ybuf  = (float*)alloc((size_t)ROWS * E_ * 4);
  unsigned short* z     = (unsigned short*)alloc((size_t)ROWS * E_ * 2);
  unsigned short* wt1   = (unsigned short*)alloc((size_t)F_ * E_ * 2);
  unsigned short* hbuf  = (unsigned short*)alloc((size_t)ROWS * F_ * 2);
  unsigned short* wt2   = (unsigned short*)alloc((size_t)E_ * F_ * 2);
  unsigned short* KF    = (unsigned short*)alloc((size_t)BH_ * S_ * D_ * 2);
  unsigned short* VF    = (unsigned short*)alloc((size_t)BH_ * S_ * D_ * 2);
  // GEMM split-K fp32 partials overlay dead y1..qkv region
  float* pA = (float*)y1;
  float* pB = pA + (size_t)ROWS * E_;
  // attention partials: 2 slices in hbuf (2 x 12.58MB), Lpart in z (dead then)
  float* Opart = (float*)hbuf;
  float* Lpart = (float*)z;

  TD d0{wq, wtqkv,                      E_, E_, 0};
  TD d1{wk, wtqkv + (size_t)E_ * E_,    E_, E_, 576};
  TD d2{wv, wtqkv + (size_t)2 * E_ * E_,E_, E_, 1152};
  TD d3{wo, wto,                        E_, E_, 1728};
  TD d4{w1, wt1,                        E_, F_, 2304};
  TD d5{w2, wt2,                        F_, E_, 4608};
  int nTot = 6912;
  dim3 tb(32, 8);
  k_tall<<<nTot + 1, tb, 0, stream>>>(d0, d1, d2, d3, d4, d5, bq, bk, bv, bqkv, nTot);

  k_ln<<<ROWS, 256, 0, stream>>>(x, ln1g, ln1b, y1);
  // QKV: WN=1, 1152 blocks (4.5/CU)
  k_gemm2<1><<<dim3(QKVN / 64, ROWS / 128), 128, 0, stream>>>(
      y1, wtqkv, bqkv, nullptr, nullptr, qkv, ROWS, QKVN, E_, E_, 4);
  k_prep<<<dim3(32, BH_), 256, 0, stream>>>(qkv, KF, VF);
  k_attn<<<dim3(S_ / 128, BH_, 2), 256, 0, stream>>>(qkv, KF, VF, Opart, Lpart);
  k_ared<<<(BH_ * S_ * 16) / 256, 256, 0, stream>>>(Opart, Lpart, ctx);
  // out-proj: WN=1, split-K=2, 768 blocks (3/CU)
  k_gemm2<1><<<dim3(E_ / 64, ROWS / 128, 2), 128, 0, stream>>>(
      ctx, wto, nullptr, nullptr, pA, nullptr, ROWS, E_, E_, E_ / 2, 8);
  k_redln<<<ROWS, 256, 0, stream>>>(pA, pB, bo, x, ln2g, ln2b, ybuf, z);
  // FFN1: WN=1, 1536 blocks (6/CU)
  k_gemm2<1><<<dim3(F_ / 64, ROWS / 128), 128, 0, stream>>>(
      z, wt1, b1, nullptr, nullptr, hbuf, ROWS, F_, E_, E_, 1 | 4);
  // FFN2: WN=1, split-K=2, 768 blocks (exactly 3/CU, balanced)
  k_gemm2<1><<<dim3(E_ / 64, ROWS / 128, 2), 128, 0, stream>>>(
      hbuf, wt2, nullptr, nullptr, pA, nullptr, ROWS, E_, F_, F_ / 2, 8);
  k_red<<<ROWS * E_ / 1024, 256, 0, stream>>>(pA, pB, b2, ybuf, out, E_);
}

// Round 9
// 315.983 us; speedup vs baseline: 1.0157x; 1.0157x over previous
//
#include <hip/hip_runtime.h>

typedef float  f32x4  __attribute__((ext_vector_type(4)));
typedef __bf16 bf16x8 __attribute__((ext_vector_type(8)));
typedef short  s16x4  __attribute__((ext_vector_type(4)));
typedef short  s16x8  __attribute__((ext_vector_type(8)));

static constexpr int B_ = 2, S_ = 2048, E_ = 768, H_ = 12, D_ = 64;
static constexpr int ROWS = B_ * S_;   // 4096
static constexpr int QKVN = 3 * E_;    // 2304
static constexpr int F_   = 4 * E_;    // 3072
static constexpr int BH_  = B_ * H_;   // 24

__device__ __forceinline__ unsigned short f2bf(float f) {
  union { float f; unsigned u; } v; v.f = f;
  unsigned r = v.u + 0x7FFFu + ((v.u >> 16) & 1u);
  return (unsigned short)(r >> 16);
}
__device__ __forceinline__ unsigned pk2(float a, float b) {
  return (unsigned)f2bf(a) | ((unsigned)f2bf(b) << 16);
}
// truncating bf16 pack (cheap; used only for P in softmax)
__device__ __forceinline__ unsigned pk2t(float a, float b) {
  union { float f; unsigned u; } x, y; x.f = a; y.f = b;
  return (x.u >> 16) | (y.u & 0xFFFF0000u);
}
__device__ __forceinline__ f32x4 mfma16(bf16x8 a, bf16x8 b, f32x4 c) {
  return __builtin_amdgcn_mfma_f32_16x16x32_bf16(a, b, c, 0, 0, 0);
}
__device__ __forceinline__ f32x4 mfma16k16(s16x4 a, s16x4 b, f32x4 c) {
  return __builtin_amdgcn_mfma_f32_16x16x16bf16_1k(a, b, c, 0, 0, 0);
}
typedef __attribute__((address_space(3))) unsigned int lds_u32;
typedef const __attribute__((address_space(1))) unsigned int glob_u32;
__device__ __forceinline__ void async_cp16(const unsigned short* g, unsigned short* l) {
  __builtin_amdgcn_global_load_lds((glob_u32*)g, (lds_u32*)l, 16, 0, 0);
}

// ---- fused: all 6 weight transposes (fp32->bf16, W(KxN)->Wt(NxK)) + bias pack ----
struct TD { const float* src; unsigned short* dst; int K; int N; int start; };
__global__ void k_tall(TD d0, TD d1, TD d2, TD d3, TD d4, TD d5,
                       const float* __restrict__ bq, const float* __restrict__ bk,
                       const float* __restrict__ bv, float* __restrict__ bqkv,
                       int nTot) {
  int bid = blockIdx.x;
  if (bid >= nTot) {  // tail block: pack QKV bias
    int t = threadIdx.y * 32 + threadIdx.x;
    for (int i = t; i < E_; i += 256) {
      bqkv[i] = bq[i]; bqkv[E_ + i] = bk[i]; bqkv[2 * E_ + i] = bv[i];
    }
    return;
  }
  TD d = d0;
  if (bid >= d1.start) d = d1;
  if (bid >= d2.start) d = d2;
  if (bid >= d3.start) d = d3;
  if (bid >= d4.start) d = d4;
  if (bid >= d5.start) d = d5;
  int local = bid - d.start;
  int tpr = d.N / 32;
  int nb = (local % tpr) * 32, kb = (local / tpr) * 32;
  __shared__ float tile[32][33];
  int tx = threadIdx.x, ty = threadIdx.y;
#pragma unroll
  for (int i = 0; i < 4; i++)
    tile[ty + 8 * i][tx] = d.src[(size_t)(kb + ty + 8 * i) * d.N + nb + tx];
  __syncthreads();
#pragma unroll
  for (int i = 0; i < 4; i++)
    d.dst[(size_t)(nb + ty + 8 * i) * d.K + kb + tx] = f2bf(tile[tx][ty + 8 * i]);
}

// ---- rearrange K and V into MFMA-fragment-ordered global buffers ----
__global__ __launch_bounds__(256) void k_prep(const unsigned short* __restrict__ qkv,
                                              unsigned short* __restrict__ KF,
                                              unsigned short* __restrict__ VF) {
  int t = blockIdx.x, bh = blockIdx.y, b = bh / H_, h = bh % H_;
  int tid = threadIdx.x;
  size_t tileBase = ((size_t)bh * 32 + t) * 4096;
  for (int it = tid; it < 512; it += 256) {
    int c = it >> 6, lane = it & 63, l15 = lane & 15, quad = lane >> 4;
    int i = c >> 1, half = c & 1;
    const unsigned short* src = qkv + (size_t)(b * S_ + t * 64 + i * 16 + l15) * QKVN
                                + E_ + h * D_ + half * 32 + quad * 8;
    *(uint4*)(KF + tileBase + (size_t)it * 8) = *(const uint4*)src;
  }
  __shared__ __align__(16) unsigned short Vt[64][72];
  for (int it = tid; it < 512; it += 256) {
    int r = it >> 3, seg = it & 7;
    const unsigned short* src = qkv + (size_t)(b * S_ + t * 64 + r) * QKVN
                                + 2 * E_ + h * D_ + seg * 8;
    *(uint4*)&Vt[r][seg * 8] = *(const uint4*)src;
  }
  __syncthreads();
  for (int it = tid; it < 512; it += 256) {
    int c = it >> 6, lane = it & 63, l15 = lane & 15, quad = lane >> 4;
    int ipair = c >> 2, ds = c & 3;
    int d = ds * 16 + l15;
    unsigned short v[8];
#pragma unroll
    for (int j = 0; j < 4; j++) {
      v[j]     = Vt[ipair * 32 + quad * 4 + j][d];
      v[4 + j] = Vt[ipair * 32 + 16 + quad * 4 + j][d];
    }
    uint4 w;
    w.x = v[0] | ((unsigned)v[1] << 16);
    w.y = v[2] | ((unsigned)v[3] << 16);
    w.z = v[4] | ((unsigned)v[5] << 16);
    w.w = v[6] | ((unsigned)v[7] << 16);
    *(uint4*)(VF + tileBase + (size_t)it * 8) = w;
  }
}

// ---- LayerNorm over E=768, one block per row, bf16 out ----
__global__ __launch_bounds__(256) void k_ln(const float* __restrict__ x,
                                            const float* __restrict__ g,
                                            const float* __restrict__ bta,
                                            unsigned short* __restrict__ y) {
  int row = blockIdx.x;
  const float* xr = x + (size_t)row * E_;
  int t = threadIdx.x;
  float v0 = xr[t], v1 = xr[t + 256], v2 = xr[t + 512];
  float s = v0 + v1 + v2, q = v0 * v0 + v1 * v1 + v2 * v2;
#pragma unroll
  for (int off = 1; off < 64; off <<= 1) {
    s += __shfl_xor(s, off);
    q += __shfl_xor(q, off);
  }
  __shared__ float ss[4], qq[4];
  int wave = t >> 6;
  if ((t & 63) == 0) { ss[wave] = s; qq[wave] = q; }
  __syncthreads();
  s = ss[0] + ss[1] + ss[2] + ss[3];
  q = qq[0] + qq[1] + qq[2] + qq[3];
  float mean = s * (1.0f / E_);
  float var  = q * (1.0f / E_) - mean * mean;
  float inv  = rsqrtf(var + 1e-5f);
  unsigned short* yr = y + (size_t)row * E_;
  yr[t]       = f2bf((v0 - mean) * inv * g[t]       + bta[t]);
  yr[t + 256] = f2bf((v1 - mean) * inv * g[t + 256] + bta[t + 256]);
  yr[t + 512] = f2bf((v2 - mean) * inv * g[t + 512] + bta[t + 512]);
}

// ---- fused split-K reduce + residual + LayerNorm ----
__global__ __launch_bounds__(256) void k_redln(const float* __restrict__ pA,
                                               const float* __restrict__ pB,
                                               const float* __restrict__ bias,
                                               const float* __restrict__ resid,
                                               const float* __restrict__ g,
                                               const float* __restrict__ bta,
                                               float* __restrict__ y,
                                               unsigned short* __restrict__ z) {
  int row = blockIdx.x;
  size_t base = (size_t)row * E_;
  int t = threadIdx.x;
  float v0 = pA[base + t]       + pB[base + t]       + bias[t]       + resid[base + t];
  float v1 = pA[base + t + 256] + pB[base + t + 256] + bias[t + 256] + resid[base + t + 256];
  float v2 = pA[base + t + 512] + pB[base + t + 512] + bias[t + 512] + resid[base + t + 512];
  y[base + t] = v0; y[base + t + 256] = v1; y[base + t + 512] = v2;
  float s = v0 + v1 + v2, q = v0 * v0 + v1 * v1 + v2 * v2;
#pragma unroll
  for (int off = 1; off < 64; off <<= 1) {
    s += __shfl_xor(s, off);
    q += __shfl_xor(q, off);
  }
  __shared__ float ss[4], qq[4];
  int wave = t >> 6;
  if ((t & 63) == 0) { ss[wave] = s; qq[wave] = q; }
  __syncthreads();
  s = ss[0] + ss[1] + ss[2] + ss[3];
  q = qq[0] + qq[1] + qq[2] + qq[3];
  float mean = s * (1.0f / E_);
  float var  = q * (1.0f / E_) - mean * mean;
  float inv  = rsqrtf(var + 1e-5f);
  unsigned short* zr = z + base;
  zr[t]       = f2bf((v0 - mean) * inv * g[t]       + bta[t]);
  zr[t + 256] = f2bf((v1 - mean) * inv * g[t + 256] + bta[t + 256]);
  zr[t + 512] = f2bf((v2 - mean) * inv * g[t + 512] + bta[t + 512]);
}

// ---- bf16 MFMA GEMM: BK=64 rounds, single-barrier double-buffered pipeline ----
// Tile 128 x (WN*64), 2*WN waves. flags: 1=gelu, 2=+resid, 4=bf16 out, 8=fp32 partial
template <int WN>
__global__ __launch_bounds__(WN * 128) void k_gemm2(
    const unsigned short* __restrict__ A, const unsigned short* __restrict__ Bt,
    const float* __restrict__ bias, const float* __restrict__ resid,
    float* __restrict__ outF, unsigned short* __restrict__ outB,
    int M, int N, int K, int kLen, int flags) {
  constexpr int NW = 2 * WN;
  __shared__ __align__(16) unsigned short Alds[2][128 * 64];      // 16KB per buf
  __shared__ __align__(16) unsigned short Blds[2][WN * 64 * 64];  // 8KB*WN per buf
  int tid = threadIdx.x, lane = tid & 63, wave = tid >> 6;
  int l15 = lane & 15, quad = lane >> 4;
  int wm = (WN == 2) ? (wave >> 1) : wave;
  int wn = (WN == 2) ? (wave & 1) : 0;
  int mblk = blockIdx.y * 128;
  int nblk = blockIdx.x * (WN * 64);
  int kOff = blockIdx.z * kLen;
  if (flags & 8) outF += (size_t)blockIdx.z * M * N;

  f32x4 acc[4][4];
#pragma unroll
  for (int i = 0; i < 4; i++)
#pragma unroll
    for (int j = 0; j < 4; j++)
#pragma unroll
      for (int r = 0; r < 4; r++) acc[i][j][r] = 0.0f;

  // chunk = 8 rows x 64 cols (one async_cp16 per 64-lane wave: lane->(row,col))
  int crow = lane >> 3, ccol = (lane & 7) * 8;
  auto stage = [&](int k0, int bufi) {
#pragma unroll
    for (int c0 = 0; c0 < 16 / NW; c0++) {
      int ch = wave + c0 * NW;
      async_cp16(A + (size_t)(mblk + ch * 8 + crow) * K + k0 + ccol,
                 Alds[bufi] + ch * 512);
    }
#pragma unroll
    for (int c0 = 0; c0 < 8 * WN / NW; c0++) {
      int ch = wave + c0 * NW;
      async_cp16(Bt + (size_t)(nblk + ch * 8 + crow) * K + k0 + ccol,
                 Blds[bufi] + ch * 512);
    }
  };

  int nT = kLen / 64;
  stage(kOff, 0);
  for (int t = 0; t < nT; t++) {
    __syncthreads();  // staging of round t complete; prior reads done
    int bufi = t & 1;
    bf16x8 af[2][4], bfj[2][4];
#pragma unroll
    for (int kk = 0; kk < 2; kk++) {
#pragma unroll
      for (int i = 0; i < 4; i++)
        af[kk][i] = *(const bf16x8*)&Alds[bufi][(wm * 64 + i * 16 + l15) * 64 + kk * 32 + quad * 8];
#pragma unroll
      for (int j = 0; j < 4; j++)
        bfj[kk][j] = *(const bf16x8*)&Blds[bufi][(wn * 64 + j * 16 + l15) * 64 + kk * 32 + quad * 8];
    }
    if (t + 1 < nT) stage(kOff + (t + 1) * 64, bufi ^ 1);  // overlap with MFMA
#pragma unroll
    for (int kk = 0; kk < 2; kk++)
#pragma unroll
      for (int i = 0; i < 4; i++)
#pragma unroll
        for (int j = 0; j < 4; j++)
          acc[i][j] = mfma16(af[kk][i], bfj[kk][j], acc[i][j]);
  }

  int m0 = mblk + wm * 64, n0 = nblk + wn * 64;
#pragma unroll
  for (int i = 0; i < 4; i++) {
#pragma unroll
    for (int j = 0; j < 4; j++) {
      int col = n0 + 16 * j + l15;
      float bcol = (flags & 8) ? 0.0f : bias[col];
#pragma unroll
      for (int r = 0; r < 4; r++) {
        int row = m0 + 16 * i + quad * 4 + r;
        float v = acc[i][j][r] + bcol;
        if (flags & 1) v = 0.5f * v * (1.0f + erff(v * 0.70710678118654752f));
        if (flags & 2) v += resid[(size_t)row * N + col];
        if (flags & 4) outB[(size_t)row * N + col] = f2bf(v);
        else           outF[(size_t)row * N + col] = v;
      }
    }
  }
}

// ---- split-K reduce: out = pA + pB + bias + resid ----
__global__ __launch_bounds__(256) void k_red(const float* __restrict__ pA,
                                             const float* __restrict__ pB,
                                             const float* __restrict__ bias,
                                             const float* __restrict__ resid,
                                             float* __restrict__ out, int N) {
  size_t i = ((size_t)blockIdx.x * 256 + threadIdx.x) * 4;
  int col = (int)(i % N);
  f32x4 a = *(const f32x4*)(pA + i);
  f32x4 b = *(const f32x4*)(pB + i);
  f32x4 c = *(const f32x4*)(bias + col);
  f32x4 r = *(const f32x4*)(resid + i);
  *(f32x4*)(out + i) = a + b + c + r;
}

// ---- flash attention: LDS-staged fragment-ordered K/V, single-barrier dbuf ----
__global__ __launch_bounds__(256, 3) void k_attn(const unsigned short* __restrict__ qkv,
                                                 const unsigned short* __restrict__ KF,
                                                 const unsigned short* __restrict__ VF,
                                                 float* __restrict__ Opart,
                                                 float* __restrict__ Lpart) {
  int bh = blockIdx.y, b = bh / H_, h = bh % H_;
  int ks = blockIdx.z;
  int tid = threadIdx.x, wave = tid >> 6, lane = tid & 63;
  int l15 = lane & 15, quad = lane >> 4;
  int q0 = blockIdx.x * 128 + wave * 32;

  __shared__ __align__(16) unsigned short Kl[2][4096];
  __shared__ __align__(16) unsigned short Vl[2][4096];

  const unsigned short* Qp = qkv + (size_t)b * S_ * QKVN + h * D_;
  bf16x8 qf[2][2];
#pragma unroll
  for (int qs = 0; qs < 2; qs++) {
    const unsigned short* qrow = Qp + (size_t)(q0 + qs * 16 + l15) * QKVN;
    qf[qs][0] = *(const bf16x8*)(qrow + quad * 8);
    qf[qs][1] = *(const bf16x8*)(qrow + 32 + quad * 8);
  }
  f32x4 o[4][2];
  float lsum[2] = {0.0f, 0.0f};
#pragma unroll
  for (int ds = 0; ds < 4; ds++)
#pragma unroll
    for (int qs = 0; qs < 2; qs++)
#pragma unroll
      for (int r = 0; r < 4; r++) o[ds][qs][r] = 0.0f;

  const float C2 = 0.03608439182435161f * 1.44269504088896341f;  // (1/sqrt(E))*log2e
  const unsigned short* KFb = KF + (size_t)bh * 32 * 4096;
  const unsigned short* VFb = VF + (size_t)bh * 32 * 4096;
  int t0 = ks * 16;

  auto stage = [&](int tt, int bufi) {
    const unsigned short* ksrc = KFb + (size_t)tt * 4096;
    const unsigned short* vsrc = VFb + (size_t)tt * 4096;
#pragma unroll
    for (int c = 0; c < 2; c++) {
      int ch = wave * 2 + c;
      async_cp16(ksrc + ch * 512 + lane * 8, Kl[bufi] + ch * 512 + lane * 8);
      async_cp16(vsrc + ch * 512 + lane * 8, Vl[bufi] + ch * 512 + lane * 8);
    }
  };

  stage(t0, 0);
  for (int tt = 0; tt < 16; tt++) {
    __syncthreads();  // staging of tile tt complete; prior reads done
    int bufi = tt & 1;
    bf16x8 kf[8];
    s16x8  vv[8];
#pragma unroll
    for (int c = 0; c < 8; c++)
      kf[c] = *(const bf16x8*)&Kl[bufi][c * 512 + lane * 8];
#pragma unroll
    for (int c = 0; c < 8; c++)
      vv[c] = *(const s16x8*)&Vl[bufi][c * 512 + lane * 8];
    if (tt + 1 < 16) stage(t0 + tt + 1, bufi ^ 1);  // overlap with compute

#pragma unroll
    for (int i = 0; i < 4; i++) {
      f32x4 s0, s1;
#pragma unroll
      for (int r = 0; r < 4; r++) { s0[r] = 0.0f; s1[r] = 0.0f; }
      s0 = mfma16(kf[i * 2], qf[0][0], s0);
      s0 = mfma16(kf[i * 2 + 1], qf[0][1], s0);
      s1 = mfma16(kf[i * 2], qf[1][0], s1);
      s1 = mfma16(kf[i * 2 + 1], qf[1][1], s1);
      float a0 = __builtin_amdgcn_exp2f(s0[0] * C2);
      float a1 = __builtin_amdgcn_exp2f(s0[1] * C2);
      float a2 = __builtin_amdgcn_exp2f(s0[2] * C2);
      float a3 = __builtin_amdgcn_exp2f(s0[3] * C2);
      float b0 = __builtin_amdgcn_exp2f(s1[0] * C2);
      float b1 = __builtin_amdgcn_exp2f(s1[1] * C2);
      float b2 = __builtin_amdgcn_exp2f(s1[2] * C2);
      float b3 = __builtin_amdgcn_exp2f(s1[3] * C2);
      lsum[0] += (a0 + a1) + (a2 + a3);
      lsum[1] += (b0 + b1) + (b2 + b3);
      union { unsigned u[2]; s16x4 s4; } pw0, pw1;
      pw0.u[0] = pk2t(a0, a1); pw0.u[1] = pk2t(a2, a3);
      pw1.u[0] = pk2t(b0, b1); pw1.u[1] = pk2t(b2, b3);
      int cb = (i >> 1) * 4;
#pragma unroll
      for (int ds = 0; ds < 4; ds++) {
        s16x4 vsel = (i & 1)
            ? __builtin_shufflevector(vv[cb + ds], vv[cb + ds], 4, 5, 6, 7)
            : __builtin_shufflevector(vv[cb + ds], vv[cb + ds], 0, 1, 2, 3);
        o[ds][0] = mfma16k16(vsel, pw0.s4, o[ds][0]);
        o[ds][1] = mfma16k16(vsel, pw1.s4, o[ds][1]);
      }
    }
  }

#pragma unroll
  for (int qs = 0; qs < 2; qs++) {
    size_t rb = (((size_t)ks * BH_ + bh) * S_ + q0 + qs * 16 + l15) * (size_t)D_;
#pragma unroll
    for (int ds = 0; ds < 4; ds++)
      *(f32x4*)(Opart + rb + ds * 16 + quad * 4) = o[ds][qs];
  }
  float l0 = lsum[0]; l0 += __shfl_xor(l0, 16); l0 += __shfl_xor(l0, 32);
  float l1 = lsum[1]; l1 += __shfl_xor(l1, 16); l1 += __shfl_xor(l1, 32);
  if (lane < 16) {
    size_t lb = ((size_t)ks * BH_ + bh) * S_ + q0;
    Lpart[lb + l15]      = l0;
    Lpart[lb + 16 + l15] = l1;
  }
}

// ---- attention split-K reduce: ctx = (O0+O1)/(l0+l1), bf16 ----
__global__ __launch_bounds__(256) void k_ared(const float* __restrict__ Op,
                                              const float* __restrict__ Lp,
                                              unsigned short* __restrict__ ctx) {
  const size_t SL = (size_t)BH_ * S_ * D_;
  const size_t LL = (size_t)BH_ * S_;
  size_t i = (size_t)blockIdx.x * 256 + threadIdx.x;
  size_t row = i >> 4;
  int d4 = (int)(i & 15);
  f32x4 a = *(const f32x4*)(Op + row * D_ + d4 * 4);
  f32x4 b = *(const f32x4*)(Op + SL + row * D_ + d4 * 4);
  float inv = 1.0f / (Lp[row] + Lp[LL + row]);
  f32x4 v = (a + b) * inv;
  int bh = (int)(row >> 11), s = (int)(row & (S_ - 1));
  int bb = bh / H_, h = bh % H_;
  uint2 w; w.x = pk2(v[0], v[1]); w.y = pk2(v[2], v[3]);
  *(uint2*)(ctx + ((size_t)bb * S_ + s) * E_ + h * D_ + d4 * 4) = w;
}

extern "C" void kernel_launch(void* const* d_in, const int* in_sizes, int n_in,
                              void* d_out, int out_size, void* d_ws, size_t ws_size,
                              hipStream_t stream) {
  const float* x    = (const float*)d_in[0];
  const float* ln1g = (const float*)d_in[1];
  const float* ln1b = (const float*)d_in[2];
  const float* wq   = (const float*)d_in[3];
  const float* bq   = (const float*)d_in[4];
  const float* wk   = (const float*)d_in[5];
  const float* bk   = (const float*)d_in[6];
  const float* wv   = (const float*)d_in[7];
  const float* bv   = (const float*)d_in[8];
  const float* wo   = (const float*)d_in[9];
  const float* bo   = (const float*)d_in[10];
  const float* w1   = (const float*)d_in[11];
  const float* b1   = (const float*)d_in[12];
  const float* w2   = (const float*)d_in[13];
  const float* b2   = (const float*)d_in[14];
  const float* ln2g = (const float*)d_in[15];
  const float* ln2b = (const float*)d_in[16];
  float* out = (float*)d_out;

  char* ws = (char*)d_ws;
  size_t off = 0;
  auto alloc = [&](size_t bytes) -> char* {
    char* p = ws + off;
    off = (off + bytes + 255) & ~(size_t)255;
    return p;
  };
  unsigned short* y1    = (unsigned short*)alloc((size_t)ROWS * E_ * 2);
  unsigned short* wtqkv = (unsigned short*)alloc((size_t)QKVN * E_ * 2);
  float*          bqkv  = (float*)alloc((size_t)QKVN * 4);
  unsigned short* qkv   = (unsigned short*)alloc((size_t)ROWS * QKVN * 2);
  unsigned short* wto   = (unsigned short*)alloc((size_t)E_ * E_ * 2);
  unsigned short* ctx   = (unsigned short*)alloc((size_t)ROWS * E_ * 2);
  float*          ybuf  = (float*)alloc((size_t)ROWS * E_ * 4);
  unsigned short* z     = (unsigned short*)alloc((size_t)ROWS * E_ * 2);
  unsigned short* wt1   = (unsigned short*)alloc((size_t)F_ * E_ * 2);
  unsigned short* hbuf  = (unsigned short*)alloc((size_t)ROWS * F_ * 2);
  unsigned short* wt2   = (unsigned short*)alloc((size_t)E_ * F_ * 2);
  unsigned short* KF    = (unsigned short*)alloc((size_t)BH_ * S_ * D_ * 2);
  unsigned short* VF    = (unsigned short*)alloc((size_t)BH_ * S_ * D_ * 2);
  // GEMM split-K fp32 partials overlay dead y1..qkv region
  float* pA = (float*)y1;
  float* pB = pA + (size_t)ROWS * E_;
  // attention partials: 2 slices in hbuf (2 x 12.58MB), Lpart in z (dead then)
  float* Opart = (float*)hbuf;
  float* Lpart = (float*)z;

  TD d0{wq, wtqkv,                      E_, E_, 0};
  TD d1{wk, wtqkv + (size_t)E_ * E_,    E_, E_, 576};
  TD d2{wv, wtqkv + (size_t)2 * E_ * E_,E_, E_, 1152};
  TD d3{wo, wto,                        E_, E_, 1728};
  TD d4{w1, wt1,                        E_, F_, 2304};
  TD d5{w2, wt2,                        F_, E_, 4608};
  int nTot = 6912;
  dim3 tb(32, 8);
  k_tall<<<nTot + 1, tb, 0, stream>>>(d0, d1, d2, d3, d4, d5, bq, bk, bv, bqkv, nTot);

  k_ln<<<ROWS, 256, 0, stream>>>(x, ln1g, ln1b, y1);
  // QKV: WN=1, BK=64, 1152 blocks, nT=12
  k_gemm2<1><<<dim3(QKVN / 64, ROWS / 128), 128, 0, stream>>>(
      y1, wtqkv, bqkv, nullptr, nullptr, qkv, ROWS, QKVN, E_, E_, 4);
  k_prep<<<dim3(32, BH_), 256, 0, stream>>>(qkv, KF, VF);
  k_attn<<<dim3(S_ / 128, BH_, 2), 256, 0, stream>>>(qkv, KF, VF, Opart, Lpart);
  k_ared<<<(BH_ * S_ * 16) / 256, 256, 0, stream>>>(Opart, Lpart, ctx);
  // out-proj: WN=1, BK=64, split-K=2, 768 blocks, nT=6
  k_gemm2<1><<<dim3(E_ / 64, ROWS / 128, 2), 128, 0, stream>>>(
      ctx, wto, nullptr, nullptr, pA, nullptr, ROWS, E_, E_, E_ / 2, 8);
  k_redln<<<ROWS, 256, 0, stream>>>(pA, pB, bo, x, ln2g, ln2b, ybuf, z);
  // FFN1: WN=1, BK=64, 1536 blocks, nT=12
  k_gemm2<1><<<dim3(F_ / 64, ROWS / 128), 128, 0, stream>>>(
      z, wt1, b1, nullptr, nullptr, hbuf, ROWS, F_, E_, E_, 1 | 4);
  // FFN2: WN=1, BK=64, split-K=2, 768 blocks, nT=24
  k_gemm2<1><<<dim3(E_ / 64, ROWS / 128, 2), 128, 0, stream>>>(
      hbuf, wt2, nullptr, nullptr, pA, nullptr, ROWS, E_, F_, F_ / 2, 8);
  k_red<<<ROWS * E_ / 1024, 256, 0, stream>>>(pA, pB, b2, ybuf, out, E_);
}